// Round 5
// baseline (44.932 us; speedup 1.0000x reference)
//
#include <hip/hip_runtime.h>
#include <math.h>

// Fused SVD rigid registration, one block (128 thr = 2 waves) per batch.
// NEW in this round: all global loads are instruction-contiguous (lane-stride
// 16B); the AoS->point-blocked transpose is done per-wave through LDS
// (linear swizzled writes, 48B-stride swizzled reads, no barriers — intra-wave
// ordering via lgkmcnt). Weights need no transpose (lane ownership matches).

constexpr int BN = 2048;  // points per batch

__device__ __forceinline__ int swz(int byte) {
    return byte ^ (((byte >> 7) & 3) << 4);   // XOR bank-group bits, 2-way max
}

__global__ __launch_bounds__(128) void svdreg_fused(
    const float* __restrict__ target,
    const float* __restrict__ source,
    const float* __restrict__ weights,
    float* __restrict__ out)
{
    const int lane = threadIdx.x & 63;
    const int wav  = threadIdx.x >> 6;  // 0..1
    const int b    = blockIdx.x;

    constexpr int ITERS = 4;  // 256 points per wave-iter, 1024 per wave

    const float4* t4 = reinterpret_cast<const float4*>(target) + (size_t)b * 1536;
    const float4* s4 = reinterpret_cast<const float4*>(source) + (size_t)b * 1536;
    const float4* w4 = reinterpret_cast<const float4*>(weights) + (size_t)b * 512;

    // LDS: per wave a 768-float t-tile + 768-float s-tile (3 KB each), linear
    // layout with XOR swizzle. Plus the 2x16 partial-moment exchange.
    __shared__ __align__(16) float lds[3072];
    __shared__ float part[2][16];
    float* myt = &lds[wav * 1536];
    float* mys = &lds[wav * 1536 + 768];

    // write indices (float units): lane l writes its loaded float4 #q (tile
    // float4 index 64q + l -> byte 1024q + 16l), swizzled.
    const int wr0 = swz(16 * lane)        >> 2;
    const int wr1 = swz(1024 + 16 * lane) >> 2;
    const int wr2 = swz(2048 + 16 * lane) >> 2;
    // read indices: lane l's 4 points = tile floats 12l..12l+11 (bytes 48l+16c)
    const int rd0 = swz(48 * lane)      >> 2;
    const int rd1 = swz(48 * lane + 16) >> 2;
    const int rd2 = swz(48 * lane + 32) >> 2;

    // [0]=W, [1..3]=sum w*t, [4..6]=sum w*s, [7..15]=M[i][j]=sum w*t_i*s_j
    float acc[16];
#pragma unroll
    for (int i = 0; i < 16; ++i) acc[i] = 0.f;

    int cb = wav * 768;   // coord tile base (float4 units), 192 per iter
    int wb = wav * 256;   // weight tile base (float4 units), 64 per iter
    float4 ct0 = t4[cb + lane], ct1 = t4[cb + 64 + lane], ct2 = t4[cb + 128 + lane];
    float4 cs0 = s4[cb + lane], cs1 = s4[cb + 64 + lane], cs2 = s4[cb + 128 + lane];
    float4 cwv = w4[wb + lane];

#pragma unroll
    for (int it = 0; it < ITERS; ++it) {
        // stage current coord tiles to LDS (linear writes, swizzled)
        *reinterpret_cast<float4*>(&myt[wr0]) = ct0;
        *reinterpret_cast<float4*>(&myt[wr1]) = ct1;
        *reinterpret_cast<float4*>(&myt[wr2]) = ct2;
        *reinterpret_cast<float4*>(&mys[wr0]) = cs0;
        *reinterpret_cast<float4*>(&mys[wr1]) = cs1;
        *reinterpret_cast<float4*>(&mys[wr2]) = cs2;

        // prefetch next tile (instruction-contiguous)
        float4 nt0, nt1, nt2, ns0, ns1, ns2, nwv;
        if (it + 1 < ITERS) {
            const int nb = cb + 192, nwb = wb + 64;
            nt0 = t4[nb + lane]; nt1 = t4[nb + 64 + lane]; nt2 = t4[nb + 128 + lane];
            ns0 = s4[nb + lane]; ns1 = s4[nb + 64 + lane]; ns2 = s4[nb + 128 + lane];
            nwv = w4[nwb + lane];
        }

        // transposed read: lane's own 4 points (12 floats per stream)
        float4 p0 = *reinterpret_cast<const float4*>(&myt[rd0]);
        float4 p1 = *reinterpret_cast<const float4*>(&myt[rd1]);
        float4 p2 = *reinterpret_cast<const float4*>(&myt[rd2]);
        float4 q0 = *reinterpret_cast<const float4*>(&mys[rd0]);
        float4 q1 = *reinterpret_cast<const float4*>(&mys[rd1]);
        float4 q2 = *reinterpret_cast<const float4*>(&mys[rd2]);

        float tx[4] = {p0.x, p0.w, p1.z, p2.y};
        float ty[4] = {p0.y, p1.x, p1.w, p2.z};
        float tz[4] = {p0.z, p1.y, p2.x, p2.w};
        float sx[4] = {q0.x, q0.w, q1.z, q2.y};
        float sy[4] = {q0.y, q1.x, q1.w, q2.z};
        float sz[4] = {q0.z, q1.y, q2.x, q2.w};
        float ww[4] = {cwv.x, cwv.y, cwv.z, cwv.w};

#pragma unroll
        for (int j = 0; j < 4; ++j) {
            float w = ww[j];
            acc[0] += w;
            float wtx = w * tx[j], wty = w * ty[j], wtz = w * tz[j];
            acc[1] += wtx;  acc[2] += wty;  acc[3] += wtz;
            acc[4] += w * sx[j]; acc[5] += w * sy[j]; acc[6] += w * sz[j];
            acc[7]  += wtx * sx[j]; acc[8]  += wtx * sy[j]; acc[9]  += wtx * sz[j];
            acc[10] += wty * sx[j]; acc[11] += wty * sy[j]; acc[12] += wty * sz[j];
            acc[13] += wtz * sx[j]; acc[14] += wtz * sy[j]; acc[15] += wtz * sz[j];
        }

        ct0 = nt0; ct1 = nt1; ct2 = nt2;
        cs0 = ns0; cs1 = ns1; cs2 = ns2;
        cwv = nwv; cb += 192; wb += 64;
    }

    // Folding multi-value wave reduction: 16 -> 8 -> 4 -> 2 -> 1 values,
    // then 2 butterfly steps. 17 shuffles total, all statically indexed.
    {
        const bool u5 = (lane & 32) != 0;
#pragma unroll
        for (int v = 0; v < 8; ++v) {
            float send = u5 ? acc[v] : acc[v + 8];
            float r = __shfl_xor(send, 32);
            acc[v] = (u5 ? acc[v + 8] : acc[v]) + r;
        }
        const bool u4 = (lane & 16) != 0;
#pragma unroll
        for (int v = 0; v < 4; ++v) {
            float send = u4 ? acc[v] : acc[v + 4];
            float r = __shfl_xor(send, 16);
            acc[v] = (u4 ? acc[v + 4] : acc[v]) + r;
        }
        const bool u3 = (lane & 8) != 0;
#pragma unroll
        for (int v = 0; v < 2; ++v) {
            float send = u3 ? acc[v] : acc[v + 2];
            float r = __shfl_xor(send, 8);
            acc[v] = (u3 ? acc[v + 2] : acc[v]) + r;
        }
        const bool u2 = (lane & 4) != 0;
        {
            float send = u2 ? acc[0] : acc[1];
            float r = __shfl_xor(send, 4);
            acc[0] = (u2 ? acc[1] : acc[0]) + r;
        }
        acc[0] += __shfl_xor(acc[0], 2);
        acc[0] += __shfl_xor(acc[0], 1);
    }

    // lane -> moment index (from the keep/send pattern): bit5->3,4->2,3->1,2->0
    const int aidx = (((lane >> 5) & 1) << 3) | (((lane >> 4) & 1) << 2) |
                     (((lane >> 3) & 1) << 1) | ((lane >> 2) & 1);
    if ((lane & 3) == 0) part[wav][aidx] = acc[0];
    __syncthreads();

    if (threadIdx.x != 0) return;

    // ---- serial tail on lane 0 of wave 0 (overlaps other blocks' mem phases)
    double v[16];
#pragma unroll
    for (int i = 0; i < 16; ++i)
        v[i] = (double)part[0][i] + (double)part[1][i];

    const double W  = v[0];
    const double Wd = W + 1e-8;
    double St[3] = {v[1], v[2], v[3]};
    double Ss[3] = {v[4], v[5], v[6]};
    double mt[3], ms[3];
#pragma unroll
    for (int i = 0; i < 3; ++i) { mt[i] = St[i] / Wd; ms[i] = Ss[i] / Wd; }

    double A[3][3];
#pragma unroll
    for (int i = 0; i < 3; ++i)
#pragma unroll
        for (int j = 0; j < 3; ++j)
            A[i][j] = v[7 + i * 3 + j] - mt[i] * Ss[j] - ms[j] * St[i] + mt[i] * ms[j] * W;

    // Det-scaled Newton polar iteration:
    //   X <- 0.5*(mu*X + (1/(mu*det))*cof(X))  ->  orthogonal polar factor U@Vh
    double X[3][3];
#pragma unroll
    for (int i = 0; i < 3; ++i)
#pragma unroll
        for (int j = 0; j < 3; ++j) X[i][j] = A[i][j];

#pragma unroll
    for (int iter = 0; iter < 10; ++iter) {
        double C[3][3];
        C[0][0] = X[1][1]*X[2][2] - X[1][2]*X[2][1];
        C[0][1] = X[1][2]*X[2][0] - X[1][0]*X[2][2];
        C[0][2] = X[1][0]*X[2][1] - X[1][1]*X[2][0];
        C[1][0] = X[0][2]*X[2][1] - X[0][1]*X[2][2];
        C[1][1] = X[0][0]*X[2][2] - X[0][2]*X[2][0];
        C[1][2] = X[0][1]*X[2][0] - X[0][0]*X[2][1];
        C[2][0] = X[0][1]*X[1][2] - X[0][2]*X[1][1];
        C[2][1] = X[0][2]*X[1][0] - X[0][0]*X[1][2];
        C[2][2] = X[0][0]*X[1][1] - X[0][1]*X[1][0];
        double det = X[0][0]*C[0][0] + X[0][1]*C[0][1] + X[0][2]*C[0][2];
        double ad  = fabs(det);
        if (!(ad > 1e-300)) { det = (det >= 0.0) ? 1e-300 : -1e-300; ad = 1e-300; }

        double mu = 1.0;
        if (iter < 6) {  // det^{-1/3} scaling accelerates early phase
            float adf = (float)ad;
            if (adf > 0.f && isfinite(adf))
                mu = (double)exp2f(-log2f(adf) * (1.0f / 3.0f));
        }
        double k1 = 0.5 * mu;
        double k2 = 0.5 / (mu * det);
#pragma unroll
        for (int i = 0; i < 3; ++i)
#pragma unroll
            for (int j = 0; j < 3; ++j)
                X[i][j] = k1 * X[i][j] + k2 * C[i][j];
    }

    double tvec[3];
#pragma unroll
    for (int i = 0; i < 3; ++i) {
        double s = mt[i];
#pragma unroll
        for (int k = 0; k < 3; ++k) s -= X[i][k] * ms[k];
        tvec[i] = s;
    }

    float4* o = reinterpret_cast<float4*>(out + (size_t)b * 16);
    o[0] = make_float4((float)X[0][0], (float)X[0][1], (float)X[0][2], (float)tvec[0]);
    o[1] = make_float4((float)X[1][0], (float)X[1][1], (float)X[1][2], (float)tvec[1]);
    o[2] = make_float4((float)X[2][0], (float)X[2][1], (float)X[2][2], (float)tvec[2]);
    o[3] = make_float4(0.f, 0.f, 0.f, 1.f);
}

extern "C" void kernel_launch(void* const* d_in, const int* in_sizes, int n_in,
                              void* d_out, int out_size, void* d_ws, size_t ws_size,
                              hipStream_t stream) {
    const float* target  = (const float*)d_in[0];
    const float* source  = (const float*)d_in[1];
    const float* weights = (const float*)d_in[2];
    float* out = (float*)d_out;

    const int B = in_sizes[2] / BN;  // weights flat = B*N
    svdreg_fused<<<B, 128, 0, stream>>>(target, source, weights, out);
}